// Round 19
// baseline (224.614 us; speedup 1.0000x reference)
//
#include <hip/hip_runtime.h>
#include <hip/hip_bf16.h>
#include <stdint.h>

// GQA prefill, all GEMM-shaped work on bf16 MFMA (16x16x32), fp32 accum.
// B=2 S=2048 E=2048 H=32 KVH=8 D=64 G=4.
// R19: transpose_v fused into the QKV GEMM epilogue. V cols (2560..3071) are
//      exactly n-tiles 20..23; those blocks write straight to Vt[b][kvh][d][s]
//      (ushort4 per thread, contiguous in s) and skip the dead QKV V-slice.
//      One fewer dispatch + one fewer 4MB read. Everything else R18-proven.

#define S_LEN 2048
#define EMB   2048
#define NH    32
#define NKVH  8
#define HD    64
#define MTOT  4096            // B*S
#define NQKV  3072            // E + 2*KVH*D
#define KDIM  2048
#define QSCALE 0.18033688011112042f   // 0.125 * log2(e)

typedef __attribute__((ext_vector_type(8))) short short8;
typedef __attribute__((ext_vector_type(4))) float f32x4;
typedef __attribute__((ext_vector_type(4))) unsigned int u32x4;
typedef unsigned int u32;

__device__ __forceinline__ unsigned short f2bf(float x) {
    unsigned int u = __builtin_bit_cast(unsigned int, x);
    u = (u + 0x7FFFu + ((u >> 16) & 1u)) >> 16;   // RTN-even
    return (unsigned short)u;
}

// v_cvt_pk_bf16_f32: low16 = bf16(a), high16 = bf16(b)
__device__ __forceinline__ u32 cvtpk_bf16(float a, float b) {
    u32 r;
    asm("v_cvt_pk_bf16_f32 %0, %1, %2" : "=v"(r) : "v"(a), "v"(b));
    return r;
}

// raw v_exp_f32 (2^x); args bounded (|x| < ~40) so no OCML wrapper needed
__device__ __forceinline__ float exp2_raw(float x) {
#if __has_builtin(__builtin_amdgcn_exp2f)
    return __builtin_amdgcn_exp2f(x);
#else
    float r;
    asm("v_exp_f32 %0, %1" : "=v"(r) : "v"(x));
    return r;
#endif
}

__device__ __forceinline__ float rcp_raw(float x) {
#if __has_builtin(__builtin_amdgcn_rcpf)
    return __builtin_amdgcn_rcpf(x);
#else
    float r;
    asm("v_rcp_f32 %0, %1" : "=v"(r) : "v"(x));
    return r;
#endif
}

#define GLOAD(src, dst)                                                                   \
    __builtin_amdgcn_global_load_lds((const __attribute__((address_space(1))) void*)(src),\
                                     (__attribute__((address_space(3))) void*)(dst), 16, 0, 0)

// --------- fused preprocessing: X cvt + all 4 weight transposes + bias concat ---------
// blockIdx.x: [0,32) Wq | [32,40) Wk | [40,48) Wv | [48,80) Wo | 80 = bias |
//             [81,113) = X fp32->bf16 (chunk id (x-81)*32 + y, 2048 float4 each).
__global__ void transpose_all(const float* __restrict__ Wq, const float* __restrict__ Wk,
                              const float* __restrict__ Wv, const float* __restrict__ Wo,
                              const float* __restrict__ bq, const float* __restrict__ bk,
                              const float* __restrict__ bv, const float* __restrict__ X,
                              unsigned short* __restrict__ Wqkvt, unsigned short* __restrict__ Wot,
                              float* __restrict__ biasq, unsigned short* __restrict__ Xb) {
    const int x = blockIdx.x;
    if (x >= 81) {
        const int chunk = (x - 81) * 32 + blockIdx.y;     // 0..1023
        const int base = chunk * 2048;                    // float4 units
        #pragma unroll
        for (int j = 0; j < 8; j++) {
            int i = base + j * 256 + threadIdx.x;
            float4 v = ((const float4*)X)[i];
            ushort4 r;
            r.x = f2bf(v.x); r.y = f2bf(v.y); r.z = f2bf(v.z); r.w = f2bf(v.w);
            ((ushort4*)Xb)[i] = r;
        }
        return;
    }
    if (x == 80) {
        if (blockIdx.y == 0)
            for (int i = threadIdx.x; i < NQKV; i += 256) {
                if (i < EMB) biasq[i] = bq[i] * QSCALE;
                else if (i < EMB + 512) biasq[i] = bk[i - EMB];
                else biasq[i] = bv[i - EMB - 512];
            }
        return;
    }
    const float* src; unsigned short* dst; int N, rowOfs, nt; float scale;
    if (x < 32)      { src = Wq; dst = Wqkvt; N = 2048; rowOfs = 0;    nt = x;      scale = QSCALE; }
    else if (x < 40) { src = Wk; dst = Wqkvt; N = 512;  rowOfs = 2048; nt = x - 32; scale = 1.0f; }
    else if (x < 48) { src = Wv; dst = Wqkvt; N = 512;  rowOfs = 2560; nt = x - 40; scale = 1.0f; }
    else             { src = Wo; dst = Wot;   N = 2048; rowOfs = 0;    nt = x - 48; scale = 1.0f; }

    __shared__ float t[64][65];
    int n0 = nt * 64, k0 = blockIdx.y * 64;
    int c = threadIdx.x & 63, r0 = threadIdx.x >> 6;
    #pragma unroll
    for (int r = r0; r < 64; r += 4) t[r][c] = src[(size_t)(k0 + r) * N + n0 + c];
    __syncthreads();
    #pragma unroll
    for (int r = r0; r < 64; r += 4)
        dst[(size_t)(rowOfs + n0 + r) * KDIM + k0 + c] = f2bf(t[c][r] * scale);
}

// --------- bf16 GEMM: A[M][2048] * Bt[N][2048]^T + bias -> C[M][N] ---------
// 128x128 tile, BK=64 (2 barriers per 64-K), XOR-swizzled LDS: row r (128B)
// holds 8 16B slots; slot s stores source col16 (s ^ (r&7)).
// XCD-aware block swizzle (grid %8==0). R17-proven.
// OUT_BF16 mode: n-tiles with n0>=2560 (the V slice) write straight to
// vt[b][kvh][d][s] (bf16) and skip the dead QKV V-slice columns.
template <bool OUT_BF16>
__global__ __launch_bounds__(256) void gemm_bt(const unsigned short* __restrict__ A,
                                               const unsigned short* __restrict__ Bt,
                                               const float* __restrict__ bias,
                                               void* __restrict__ Cout, int N,
                                               unsigned short* __restrict__ vt) {
    __shared__ __align__(16) unsigned short As[128 * 64];
    __shared__ __align__(16) unsigned short Bs[128 * 64];
    const int t = threadIdx.x;
    const int lane = t & 63;
    const int l15 = lane & 15, hi = lane >> 4;
    const int xsw = l15 & 7;
    const int w = t >> 6;
    const int wm = (w >> 1) * 64, wn = (w & 1) * 64;

    const unsigned nbx = gridDim.x;
    const unsigned flat = blockIdx.y * nbx + blockIdx.x;
    const unsigned cpx = (nbx * gridDim.y) >> 3;           // nwg/8; nwg%8==0
    const unsigned swz = (flat & 7u) * cpx + (flat >> 3);  // XCD-contiguous tiles
    const int m0 = (int)(swz / nbx) * 128, n0 = (int)(swz % nbx) * 128;

    const int srow = t >> 3;                     // 0..31 (chunk adds c*32)
    const int scol = ((t & 7) ^ (srow & 7)) * 8; // pre-swizzled source col (elems)
    const unsigned short* ag[4];
    const unsigned short* bg[4];
    #pragma unroll
    for (int c = 0; c < 4; c++) {
        ag[c] = A  + (size_t)(m0 + c * 32 + srow) * KDIM + scol;
        bg[c] = Bt + (size_t)(n0 + c * 32 + srow) * KDIM + scol;
    }

    f32x4 acc[4][4] = {};

    for (int k0 = 0; k0 < KDIM; k0 += 64) {
        #pragma unroll
        for (int c = 0; c < 4; c++) {
            GLOAD(ag[c] + k0, As + c * 2048 + t * 8);
            GLOAD(bg[c] + k0, Bs + c * 2048 + t * 8);
        }
        __syncthreads();
        #pragma unroll
        for (int ks = 0; ks < 2; ks++) {
            short8 af[4], bf[4];
            #pragma unroll
            for (int m = 0; m < 4; m++)
                af[m] = *(const short8*)(As + (wm + m * 16 + l15) * 64 + (((ks * 4 + hi) ^ xsw) * 8));
            #pragma unroll
            for (int n = 0; n < 4; n++)
                bf[n] = *(const short8*)(Bs + (wn + n * 16 + l15) * 64 + (((ks * 4 + hi) ^ xsw) * 8));
            __builtin_amdgcn_s_setprio(1);
            #pragma unroll
            for (int m = 0; m < 4; m++)
                #pragma unroll
                for (int n = 0; n < 4; n++)
                    acc[m][n] = __builtin_amdgcn_mfma_f32_16x16x32_bf16(af[m], bf[n], acc[m][n], 0, 0, 0);
            __builtin_amdgcn_s_setprio(0);
        }
        __syncthreads();
    }

    if (OUT_BF16 && n0 >= EMB + 512) {
        // V n-tiles -> Vt[b][kvh][d][s]; 4 consecutive s per thread (ushort4)
        #pragma unroll
        for (int m = 0; m < 4; m++) {
            int row = m0 + wm + m * 16 + hi * 4;
            int bb_ = row >> 11, s = row & 2047;
            #pragma unroll
            for (int n = 0; n < 4; n++) {
                int col = n0 + wn + n * 16 + l15;
                float bb = bias[col];
                int vcol = col - (EMB + 512);
                unsigned short* dst = vt +
                    ((size_t)(bb_ * NKVH + (vcol >> 6)) * HD + (vcol & 63)) * S_LEN + s;
                ushort4 pk;
                pk.x = f2bf(acc[m][n][0] + bb);
                pk.y = f2bf(acc[m][n][1] + bb);
                pk.z = f2bf(acc[m][n][2] + bb);
                pk.w = f2bf(acc[m][n][3] + bb);
                *(ushort4*)dst = pk;
            }
        }
        return;
    }

    #pragma unroll
    for (int m = 0; m < 4; m++) {
        int row = m0 + wm + m * 16 + hi * 4;
        #pragma unroll
        for (int n = 0; n < 4; n++) {
            int col = n0 + wn + n * 16 + l15;
            float bb = bias[col];
            #pragma unroll
            for (int i = 0; i < 4; i++) {
                float v = acc[m][n][i] + bb;
                if (OUT_BF16) ((unsigned short*)Cout)[(size_t)(row + i) * N + col] = f2bf(v);
                else          ((float*)Cout)[(size_t)(row + i) * N + col] = v;
            }
        }
    }
}

// --------- flash attention: 8 waves x 32 q-rows, shared K/V dbuf, no-max softmax ---------
// R12-proven ROLLED loop (runtime buffer index) — do not unroll (R13/R14).
__global__ __launch_bounds__(512, 4) void attn(const unsigned short* __restrict__ qkv,
                                               const unsigned short* __restrict__ vt,
                                               unsigned short* __restrict__ out) {
    constexpr int NT = S_LEN / 64;
    const int qt = blockIdx.x, h = blockIdx.y, b = blockIdx.z;
    const int kvh = h >> 2;
    const int t = threadIdx.x, lane = t & 63, w = t >> 6;
    const int l15 = lane & 15, hi = lane >> 4;
    const int xsw = l15 & 7;

    __shared__ __align__(16) unsigned short Ks[2][64 * 64];
    __shared__ __align__(16) unsigned short Vs[2][64 * 64];

    // shfl source lanes for the P repack (R3-proven)
    const int grpA = ((hi & 1) << 1) | (hi >> 1);
    const int laneA = l15 + grpA * 16;
    const int laneB = laneA ^ 16;
    const bool top = hi >= 2;

    // bf16 ones fragment for the column-sum MFMA; persistent zero C
    u32x4 onesw;
    onesw[0] = 0x3F803F80u; onesw[1] = 0x3F803F80u; onesw[2] = 0x3F803F80u; onesw[3] = 0x3F803F80u;
    const short8 ones = __builtin_bit_cast(short8, onesw);
    const f32x4 fzero = {};

    const int qrow0 = b * S_LEN + qt * 256 + w * 32;
    short8 qf[2][2];  // [nt][ks]
    #pragma unroll
    for (int nt = 0; nt < 2; nt++)
        #pragma unroll
        for (int ks = 0; ks < 2; ks++)
            qf[nt][ks] = *(const short8*)(qkv + (size_t)(qrow0 + nt * 16 + l15) * NQKV + h * HD + ks * 32 + hi * 8);

    f32x4 o[4][2] = {};              // [dt][nt]
    f32x4 osum[2] = {};              // column sums of P

    const unsigned short* kbase = qkv + (size_t)b * S_LEN * NQKV + EMB + kvh * HD;
    const unsigned short* vbase = vt + (size_t)(b * NKVH + kvh) * HD * S_LEN;

    // staging source pointers (source pre-swizzled so linear LDS dest + XOR read works)
    const int sr = t >> 3;                       // dest row (0..63)
    const int sc16 = ((t & 7) ^ (sr & 7)) * 8;   // pre-swizzled source col (shorts)
    const unsigned short* kg0 = kbase + (size_t)sr * NQKV + sc16;
    const unsigned short* vg0 = vbase + (size_t)sr * S_LEN + sc16;

#define STAGE(buf, kv0)                                               \
    do {                                                              \
        GLOAD(kg0 + (size_t)(kv0) * NQKV, &Ks[buf][t * 8]);           \
        GLOAD(vg0 + (kv0),                &Vs[buf][t * 8]);           \
    } while (0)

    STAGE(0, 0);
    __syncthreads();

    for (int tt = 0; tt < NT; tt++) {
        const int cur = tt & 1;
        if (tt + 1 < NT) STAGE(cur ^ 1, (tt + 1) * 64);

        const unsigned short* Kc = Ks[cur];
        const unsigned short* Vc = Vs[cur];

        // ---- S^T = K Q^T (log2 units); ks=0 uses zero C (no per-tile re-init) ----
        f32x4 sc[4][2];              // [mt(k)][nt(q)]
        {
            short8 kf[4];
            #pragma unroll
            for (int mt = 0; mt < 4; mt++)
                kf[mt] = *(const short8*)(Kc + (mt * 16 + l15) * 64 + ((hi ^ xsw) * 8));
            __builtin_amdgcn_s_setprio(1);
            #pragma unroll
            for (int mt = 0; mt < 4; mt++)
                #pragma unroll
                for (int nt = 0; nt < 2; nt++)
                    sc[mt][nt] = __builtin_amdgcn_mfma_f32_16x16x32_bf16(kf[mt], qf[nt][0], fzero, 0, 0, 0);
            __builtin_amdgcn_s_setprio(0);
        }
        {
            short8 kf[4];
            #pragma unroll
            for (int mt = 0; mt < 4; mt++)
                kf[mt] = *(const short8*)(Kc + (mt * 16 + l15) * 64 + (((4 + hi) ^ xsw) * 8));
            __builtin_amdgcn_s_setprio(1);
            #pragma unroll
            for (int mt = 0; mt < 4; mt++)
                #pragma unroll
                for (int nt = 0; nt < 2; nt++)
                    sc[mt][nt] = __builtin_amdgcn_mfma_f32_16x16x32_bf16(kf[mt], qf[nt][1], sc[mt][nt], 0, 0, 0);
            __builtin_amdgcn_s_setprio(0);
        }

        // ---- P = exp2(S) elementwise (raw v_exp_f32); pack to bf16 ----
        u32 w0[4][2], w1[4][2];      // packed bf16 P pairs [mt][nt]
        #pragma unroll
        for (int nt = 0; nt < 2; nt++)
            #pragma unroll
            for (int mt = 0; mt < 4; mt++) {
                #pragma unroll
                for (int i = 0; i < 4; i++)
                    sc[mt][nt][i] = exp2_raw(sc[mt][nt][i]);
                w0[mt][nt] = cvtpk_bf16(sc[mt][nt][0], sc[mt][nt][1]);
                w1[mt][nt] = cvtpk_bf16(sc[mt][nt][2], sc[mt][nt][3]);
            }

        // ---- in-register P repack (shfl) + O += V^T P, sum += 1^T P ----
        #pragma unroll
        for (int ks = 0; ks < 2; ks++) {
            short8 vf[4];
            #pragma unroll
            for (int dt = 0; dt < 4; dt++)
                vf[dt] = *(const short8*)(Vc + (dt * 16 + l15) * 64 + (((ks * 4 + hi) ^ xsw) * 8));
            #pragma unroll
            for (int nt = 0; nt < 2; nt++) {
                u32 a0 = (hi & 1) ? w0[2 * ks + 1][nt] : w0[2 * ks][nt];
                u32 a1 = (hi & 1) ? w1[2 * ks + 1][nt] : w1[2 * ks][nt];
                u32 b0 = (hi & 1) ? w0[2 * ks][nt] : w0[2 * ks + 1][nt];
                u32 b1 = (hi & 1) ? w1[2 * ks][nt] : w1[2 * ks + 1][nt];
                u32 r0 = (u32)__shfl((int)a0, laneA);
                u32 r1 = (u32)__shfl((int)a1, laneA);
                u32 r2 = (u32)__shfl((int)b0, laneB);
                u32 r3 = (u32)__shfl((int)b1, laneB);
                u32x4 pw;
                pw[0] = top ? r2 : r0;
                pw[1] = top ? r3 : r1;
                pw[2] = top ? r0 : r2;
                pw[3] = top ? r1 : r3;
                short8 pa = __builtin_bit_cast(short8, pw);
                __builtin_amdgcn_s_setprio(1);
                osum[nt] = __builtin_amdgcn_mfma_f32_16x16x32_bf16(ones, pa, osum[nt], 0, 0, 0);
                #pragma unroll
                for (int dt = 0; dt < 4; dt++)
                    o[dt][nt] = __builtin_amdgcn_mfma_f32_16x16x32_bf16(vf[dt], pa, o[dt][nt], 0, 0, 0);
                __builtin_amdgcn_s_setprio(0);
            }
        }
        __syncthreads();   // drains stage(tt+1) vmem; protects buffer reuse
    }
#undef STAGE

    // ---- normalize + write (O^T layout: row=d, col=q); packed stores ----
    #pragma unroll
    for (int nt = 0; nt < 2; nt++) {
        float inv = rcp_raw(osum[nt][0]);
        size_t rbase = (size_t)(qrow0 + nt * 16 + l15) * EMB + h * HD;
        #pragma unroll
        for (int dt = 0; dt < 4; dt++) {
            uint2 pk;
            pk.x = cvtpk_bf16(o[dt][nt][0] * inv, o[dt][nt][1] * inv);
            pk.y = cvtpk_bf16(o[dt][nt][2] * inv, o[dt][nt][3] * inv);
            *(uint2*)(out + rbase + dt * 16 + hi * 4) = pk;
        }
    }
}

extern "C" void kernel_launch(void* const* d_in, const int* in_sizes, int n_in,
                              void* d_out, int out_size, void* d_ws, size_t ws_size,
                              hipStream_t stream) {
    const float* datas = (const float*)d_in[0];
    const float* Wq = (const float*)d_in[1];
    const float* bq = (const float*)d_in[2];
    const float* Wk = (const float*)d_in[3];
    const float* bk = (const float*)d_in[4];
    const float* Wv = (const float*)d_in[5];
    const float* bv = (const float*)d_in[6];
    const float* Wo = (const float*)d_in[7];
    const float* bo = (const float*)d_in[8];
    float* out = (float*)d_out;

    char* ws = (char*)d_ws;
    unsigned short* Xb = (unsigned short*)ws;      ws += (size_t)MTOT * KDIM * 2;
    unsigned short* Wqkvt = (unsigned short*)ws;   ws += (size_t)NQKV * KDIM * 2;
    unsigned short* Wot = (unsigned short*)ws;     ws += (size_t)EMB * KDIM * 2;
    float* biasq = (float*)ws;                     ws += (size_t)NQKV * 4;
    unsigned short* QKV = (unsigned short*)ws;     ws += (size_t)MTOT * NQKV * 2;
    unsigned short* Vt = (unsigned short*)ws;      ws += (size_t)2 * NKVH * HD * S_LEN * 2;
    unsigned short* AO = (unsigned short*)ws;      ws += (size_t)MTOT * EMB * 2;

    transpose_all<<<dim3(113, 32), 256, 0, stream>>>(Wq, Wk, Wv, Wo, bq, bk, bv, datas,
                                                     Wqkvt, Wot, biasq, Xb);

    gemm_bt<true><<<dim3(NQKV / 128, MTOT / 128), 256, 0, stream>>>(Xb, Wqkvt, biasq, QKV, NQKV, Vt);
    attn<<<dim3(S_LEN / 256, NH, 2), 512, 0, stream>>>(QKV, Vt, AO);
    gemm_bt<false><<<dim3(EMB / 128, MTOT / 128), 256, 0, stream>>>(AO, Wot, bo, out, EMB, nullptr);
}

// Round 20
// 211.524 us; speedup vs baseline: 1.0619x; 1.0619x over previous
//
#include <hip/hip_runtime.h>
#include <hip/hip_bf16.h>
#include <stdint.h>

// GQA prefill, all GEMM-shaped work on bf16 MFMA (16x16x32), fp32 accum.
// B=2 S=2048 E=2048 H=32 KVH=8 D=64 G=4.
// R20: exact revert to R18 (212.1 µs proven). R19's Vt-fusion regressed +12.5 µs:
//      the fused epilogue scattered each wave's V-store across 64 rows (4 KB
//      stride, 8 B/lane) — the standalone LDS-based transpose_v is cheaper.

#define S_LEN 2048
#define EMB   2048
#define NH    32
#define NKVH  8
#define HD    64
#define MTOT  4096            // B*S
#define NQKV  3072            // E + 2*KVH*D
#define KDIM  2048
#define QSCALE 0.18033688011112042f   // 0.125 * log2(e)

typedef __attribute__((ext_vector_type(8))) short short8;
typedef __attribute__((ext_vector_type(4))) float f32x4;
typedef __attribute__((ext_vector_type(4))) unsigned int u32x4;
typedef unsigned int u32;

__device__ __forceinline__ unsigned short f2bf(float x) {
    unsigned int u = __builtin_bit_cast(unsigned int, x);
    u = (u + 0x7FFFu + ((u >> 16) & 1u)) >> 16;   // RTN-even
    return (unsigned short)u;
}

// v_cvt_pk_bf16_f32: low16 = bf16(a), high16 = bf16(b)
__device__ __forceinline__ u32 cvtpk_bf16(float a, float b) {
    u32 r;
    asm("v_cvt_pk_bf16_f32 %0, %1, %2" : "=v"(r) : "v"(a), "v"(b));
    return r;
}

// raw v_exp_f32 (2^x); args bounded (|x| < ~40) so no OCML wrapper needed
__device__ __forceinline__ float exp2_raw(float x) {
#if __has_builtin(__builtin_amdgcn_exp2f)
    return __builtin_amdgcn_exp2f(x);
#else
    float r;
    asm("v_exp_f32 %0, %1" : "=v"(r) : "v"(x));
    return r;
#endif
}

__device__ __forceinline__ float rcp_raw(float x) {
#if __has_builtin(__builtin_amdgcn_rcpf)
    return __builtin_amdgcn_rcpf(x);
#else
    float r;
    asm("v_rcp_f32 %0, %1" : "=v"(r) : "v"(x));
    return r;
#endif
}

#define GLOAD(src, dst)                                                                   \
    __builtin_amdgcn_global_load_lds((const __attribute__((address_space(1))) void*)(src),\
                                     (__attribute__((address_space(3))) void*)(dst), 16, 0, 0)

// --------- fused preprocessing: X cvt + all 4 weight transposes + bias concat ---------
// blockIdx.x: [0,32) Wq | [32,40) Wk | [40,48) Wv | [48,80) Wo | 80 = bias |
//             [81,113) = X fp32->bf16 (chunk id (x-81)*32 + y, 2048 float4 each).
__global__ void transpose_all(const float* __restrict__ Wq, const float* __restrict__ Wk,
                              const float* __restrict__ Wv, const float* __restrict__ Wo,
                              const float* __restrict__ bq, const float* __restrict__ bk,
                              const float* __restrict__ bv, const float* __restrict__ X,
                              unsigned short* __restrict__ Wqkvt, unsigned short* __restrict__ Wot,
                              float* __restrict__ biasq, unsigned short* __restrict__ Xb) {
    const int x = blockIdx.x;
    if (x >= 81) {
        const int chunk = (x - 81) * 32 + blockIdx.y;     // 0..1023
        const int base = chunk * 2048;                    // float4 units
        #pragma unroll
        for (int j = 0; j < 8; j++) {
            int i = base + j * 256 + threadIdx.x;
            float4 v = ((const float4*)X)[i];
            ushort4 r;
            r.x = f2bf(v.x); r.y = f2bf(v.y); r.z = f2bf(v.z); r.w = f2bf(v.w);
            ((ushort4*)Xb)[i] = r;
        }
        return;
    }
    if (x == 80) {
        if (blockIdx.y == 0)
            for (int i = threadIdx.x; i < NQKV; i += 256) {
                if (i < EMB) biasq[i] = bq[i] * QSCALE;
                else if (i < EMB + 512) biasq[i] = bk[i - EMB];
                else biasq[i] = bv[i - EMB - 512];
            }
        return;
    }
    const float* src; unsigned short* dst; int N, rowOfs, nt; float scale;
    if (x < 32)      { src = Wq; dst = Wqkvt; N = 2048; rowOfs = 0;    nt = x;      scale = QSCALE; }
    else if (x < 40) { src = Wk; dst = Wqkvt; N = 512;  rowOfs = 2048; nt = x - 32; scale = 1.0f; }
    else if (x < 48) { src = Wv; dst = Wqkvt; N = 512;  rowOfs = 2560; nt = x - 40; scale = 1.0f; }
    else             { src = Wo; dst = Wot;   N = 2048; rowOfs = 0;    nt = x - 48; scale = 1.0f; }

    __shared__ float t[64][65];
    int n0 = nt * 64, k0 = blockIdx.y * 64;
    int c = threadIdx.x & 63, r0 = threadIdx.x >> 6;
    #pragma unroll
    for (int r = r0; r < 64; r += 4) t[r][c] = src[(size_t)(k0 + r) * N + n0 + c];
    __syncthreads();
    #pragma unroll
    for (int r = r0; r < 64; r += 4)
        dst[(size_t)(rowOfs + n0 + r) * KDIM + k0 + c] = f2bf(t[c][r] * scale);
}

// --------- transpose V slice of QKV -> Vt[b][kvh][d][s] (bf16) ---------
__global__ void transpose_v(const unsigned short* __restrict__ qkv, unsigned short* __restrict__ vt) {
    __shared__ unsigned short t[64][72];
    int s0 = blockIdx.x * 64; int kvh = blockIdx.y; int b = blockIdx.z;
    int c = threadIdx.x & 63, r0 = threadIdx.x >> 6;
    #pragma unroll
    for (int r = r0; r < 64; r += 4)
        t[r][c] = qkv[(size_t)(b * S_LEN + s0 + r) * NQKV + (EMB + NKVH * HD) + kvh * HD + c];
    __syncthreads();
    #pragma unroll
    for (int r = r0; r < 64; r += 4)
        vt[(size_t)((b * NKVH + kvh) * HD + r) * S_LEN + s0 + c] = t[c][r];
}

// --------- bf16 GEMM: A[M][2048] * Bt[N][2048]^T + bias -> C[M][N] ---------
// 128x128 tile, BK=64 (2 barriers per 64-K), XOR-swizzled LDS: row r (128B)
// holds 8 16B slots; slot s stores source col16 (s ^ (r&7)).
// XCD-aware block swizzle (grid %8==0). R17-proven.
template <bool OUT_BF16>
__global__ __launch_bounds__(256) void gemm_bt(const unsigned short* __restrict__ A,
                                               const unsigned short* __restrict__ Bt,
                                               const float* __restrict__ bias,
                                               void* __restrict__ Cout, int N) {
    __shared__ __align__(16) unsigned short As[128 * 64];
    __shared__ __align__(16) unsigned short Bs[128 * 64];
    const int t = threadIdx.x;
    const int lane = t & 63;
    const int l15 = lane & 15, hi = lane >> 4;
    const int xsw = l15 & 7;
    const int w = t >> 6;
    const int wm = (w >> 1) * 64, wn = (w & 1) * 64;

    const unsigned nbx = gridDim.x;
    const unsigned flat = blockIdx.y * nbx + blockIdx.x;
    const unsigned cpx = (nbx * gridDim.y) >> 3;           // nwg/8; nwg%8==0
    const unsigned swz = (flat & 7u) * cpx + (flat >> 3);  // XCD-contiguous tiles
    const int m0 = (int)(swz / nbx) * 128, n0 = (int)(swz % nbx) * 128;

    const int srow = t >> 3;                     // 0..31 (chunk adds c*32)
    const int scol = ((t & 7) ^ (srow & 7)) * 8; // pre-swizzled source col (elems)
    const unsigned short* ag[4];
    const unsigned short* bg[4];
    #pragma unroll
    for (int c = 0; c < 4; c++) {
        ag[c] = A  + (size_t)(m0 + c * 32 + srow) * KDIM + scol;
        bg[c] = Bt + (size_t)(n0 + c * 32 + srow) * KDIM + scol;
    }

    f32x4 acc[4][4] = {};

    for (int k0 = 0; k0 < KDIM; k0 += 64) {
        #pragma unroll
        for (int c = 0; c < 4; c++) {
            GLOAD(ag[c] + k0, As + c * 2048 + t * 8);
            GLOAD(bg[c] + k0, Bs + c * 2048 + t * 8);
        }
        __syncthreads();
        #pragma unroll
        for (int ks = 0; ks < 2; ks++) {
            short8 af[4], bf[4];
            #pragma unroll
            for (int m = 0; m < 4; m++)
                af[m] = *(const short8*)(As + (wm + m * 16 + l15) * 64 + (((ks * 4 + hi) ^ xsw) * 8));
            #pragma unroll
            for (int n = 0; n < 4; n++)
                bf[n] = *(const short8*)(Bs + (wn + n * 16 + l15) * 64 + (((ks * 4 + hi) ^ xsw) * 8));
            __builtin_amdgcn_s_setprio(1);
            #pragma unroll
            for (int m = 0; m < 4; m++)
                #pragma unroll
                for (int n = 0; n < 4; n++)
                    acc[m][n] = __builtin_amdgcn_mfma_f32_16x16x32_bf16(af[m], bf[n], acc[m][n], 0, 0, 0);
            __builtin_amdgcn_s_setprio(0);
        }
        __syncthreads();
    }

    #pragma unroll
    for (int m = 0; m < 4; m++) {
        int row = m0 + wm + m * 16 + hi * 4;
        #pragma unroll
        for (int n = 0; n < 4; n++) {
            int col = n0 + wn + n * 16 + l15;
            float bb = bias[col];
            #pragma unroll
            for (int i = 0; i < 4; i++) {
                float v = acc[m][n][i] + bb;
                if (OUT_BF16) ((unsigned short*)Cout)[(size_t)(row + i) * N + col] = f2bf(v);
                else          ((float*)Cout)[(size_t)(row + i) * N + col] = v;
            }
        }
    }
}

// --------- flash attention: 8 waves x 32 q-rows, shared K/V dbuf, no-max softmax ---------
// R12-proven ROLLED loop (runtime buffer index) — do not unroll (R13/R14).
__global__ __launch_bounds__(512, 4) void attn(const unsigned short* __restrict__ qkv,
                                               const unsigned short* __restrict__ vt,
                                               unsigned short* __restrict__ out) {
    constexpr int NT = S_LEN / 64;
    const int qt = blockIdx.x, h = blockIdx.y, b = blockIdx.z;
    const int kvh = h >> 2;
    const int t = threadIdx.x, lane = t & 63, w = t >> 6;
    const int l15 = lane & 15, hi = lane >> 4;
    const int xsw = l15 & 7;

    __shared__ __align__(16) unsigned short Ks[2][64 * 64];
    __shared__ __align__(16) unsigned short Vs[2][64 * 64];

    // shfl source lanes for the P repack (R3-proven)
    const int grpA = ((hi & 1) << 1) | (hi >> 1);
    const int laneA = l15 + grpA * 16;
    const int laneB = laneA ^ 16;
    const bool top = hi >= 2;

    // bf16 ones fragment for the column-sum MFMA; persistent zero C
    u32x4 onesw;
    onesw[0] = 0x3F803F80u; onesw[1] = 0x3F803F80u; onesw[2] = 0x3F803F80u; onesw[3] = 0x3F803F80u;
    const short8 ones = __builtin_bit_cast(short8, onesw);
    const f32x4 fzero = {};

    const int qrow0 = b * S_LEN + qt * 256 + w * 32;
    short8 qf[2][2];  // [nt][ks]
    #pragma unroll
    for (int nt = 0; nt < 2; nt++)
        #pragma unroll
        for (int ks = 0; ks < 2; ks++)
            qf[nt][ks] = *(const short8*)(qkv + (size_t)(qrow0 + nt * 16 + l15) * NQKV + h * HD + ks * 32 + hi * 8);

    f32x4 o[4][2] = {};              // [dt][nt]
    f32x4 osum[2] = {};              // column sums of P

    const unsigned short* kbase = qkv + (size_t)b * S_LEN * NQKV + EMB + kvh * HD;
    const unsigned short* vbase = vt + (size_t)(b * NKVH + kvh) * HD * S_LEN;

    // staging source pointers (source pre-swizzled so linear LDS dest + XOR read works)
    const int sr = t >> 3;                       // dest row (0..63)
    const int sc16 = ((t & 7) ^ (sr & 7)) * 8;   // pre-swizzled source col (shorts)
    const unsigned short* kg0 = kbase + (size_t)sr * NQKV + sc16;
    const unsigned short* vg0 = vbase + (size_t)sr * S_LEN + sc16;

#define STAGE(buf, kv0)                                               \
    do {                                                              \
        GLOAD(kg0 + (size_t)(kv0) * NQKV, &Ks[buf][t * 8]);           \
        GLOAD(vg0 + (kv0),                &Vs[buf][t * 8]);           \
    } while (0)

    STAGE(0, 0);
    __syncthreads();

    for (int tt = 0; tt < NT; tt++) {
        const int cur = tt & 1;
        if (tt + 1 < NT) STAGE(cur ^ 1, (tt + 1) * 64);

        const unsigned short* Kc = Ks[cur];
        const unsigned short* Vc = Vs[cur];

        // ---- S^T = K Q^T (log2 units); ks=0 uses zero C (no per-tile re-init) ----
        f32x4 sc[4][2];              // [mt(k)][nt(q)]
        {
            short8 kf[4];
            #pragma unroll
            for (int mt = 0; mt < 4; mt++)
                kf[mt] = *(const short8*)(Kc + (mt * 16 + l15) * 64 + ((hi ^ xsw) * 8));
            __builtin_amdgcn_s_setprio(1);
            #pragma unroll
            for (int mt = 0; mt < 4; mt++)
                #pragma unroll
                for (int nt = 0; nt < 2; nt++)
                    sc[mt][nt] = __builtin_amdgcn_mfma_f32_16x16x32_bf16(kf[mt], qf[nt][0], fzero, 0, 0, 0);
            __builtin_amdgcn_s_setprio(0);
        }
        {
            short8 kf[4];
            #pragma unroll
            for (int mt = 0; mt < 4; mt++)
                kf[mt] = *(const short8*)(Kc + (mt * 16 + l15) * 64 + (((4 + hi) ^ xsw) * 8));
            __builtin_amdgcn_s_setprio(1);
            #pragma unroll
            for (int mt = 0; mt < 4; mt++)
                #pragma unroll
                for (int nt = 0; nt < 2; nt++)
                    sc[mt][nt] = __builtin_amdgcn_mfma_f32_16x16x32_bf16(kf[mt], qf[nt][1], sc[mt][nt], 0, 0, 0);
            __builtin_amdgcn_s_setprio(0);
        }

        // ---- P = exp2(S) elementwise (raw v_exp_f32); pack to bf16 ----
        u32 w0[4][2], w1[4][2];      // packed bf16 P pairs [mt][nt]
        #pragma unroll
        for (int nt = 0; nt < 2; nt++)
            #pragma unroll
            for (int mt = 0; mt < 4; mt++) {
                #pragma unroll
                for (int i = 0; i < 4; i++)
                    sc[mt][nt][i] = exp2_raw(sc[mt][nt][i]);
                w0[mt][nt] = cvtpk_bf16(sc[mt][nt][0], sc[mt][nt][1]);
                w1[mt][nt] = cvtpk_bf16(sc[mt][nt][2], sc[mt][nt][3]);
            }

        // ---- in-register P repack (shfl) + O += V^T P, sum += 1^T P ----
        #pragma unroll
        for (int ks = 0; ks < 2; ks++) {
            short8 vf[4];
            #pragma unroll
            for (int dt = 0; dt < 4; dt++)
                vf[dt] = *(const short8*)(Vc + (dt * 16 + l15) * 64 + (((ks * 4 + hi) ^ xsw) * 8));
            #pragma unroll
            for (int nt = 0; nt < 2; nt++) {
                u32 a0 = (hi & 1) ? w0[2 * ks + 1][nt] : w0[2 * ks][nt];
                u32 a1 = (hi & 1) ? w1[2 * ks + 1][nt] : w1[2 * ks][nt];
                u32 b0 = (hi & 1) ? w0[2 * ks][nt] : w0[2 * ks + 1][nt];
                u32 b1 = (hi & 1) ? w1[2 * ks][nt] : w1[2 * ks + 1][nt];
                u32 r0 = (u32)__shfl((int)a0, laneA);
                u32 r1 = (u32)__shfl((int)a1, laneA);
                u32 r2 = (u32)__shfl((int)b0, laneB);
                u32 r3 = (u32)__shfl((int)b1, laneB);
                u32x4 pw;
                pw[0] = top ? r2 : r0;
                pw[1] = top ? r3 : r1;
                pw[2] = top ? r0 : r2;
                pw[3] = top ? r1 : r3;
                short8 pa = __builtin_bit_cast(short8, pw);
                __builtin_amdgcn_s_setprio(1);
                osum[nt] = __builtin_amdgcn_mfma_f32_16x16x32_bf16(ones, pa, osum[nt], 0, 0, 0);
                #pragma unroll
                for (int dt = 0; dt < 4; dt++)
                    o[dt][nt] = __builtin_amdgcn_mfma_f32_16x16x32_bf16(vf[dt], pa, o[dt][nt], 0, 0, 0);
                __builtin_amdgcn_s_setprio(0);
            }
        }
        __syncthreads();   // drains stage(tt+1) vmem; protects buffer reuse
    }
#undef STAGE

    // ---- normalize + write (O^T layout: row=d, col=q); packed stores ----
    #pragma unroll
    for (int nt = 0; nt < 2; nt++) {
        float inv = rcp_raw(osum[nt][0]);
        size_t rbase = (size_t)(qrow0 + nt * 16 + l15) * EMB + h * HD;
        #pragma unroll
        for (int dt = 0; dt < 4; dt++) {
            uint2 pk;
            pk.x = cvtpk_bf16(o[dt][nt][0] * inv, o[dt][nt][1] * inv);
            pk.y = cvtpk_bf16(o[dt][nt][2] * inv, o[dt][nt][3] * inv);
            *(uint2*)(out + rbase + dt * 16 + hi * 4) = pk;
        }
    }
}

extern "C" void kernel_launch(void* const* d_in, const int* in_sizes, int n_in,
                              void* d_out, int out_size, void* d_ws, size_t ws_size,
                              hipStream_t stream) {
    const float* datas = (const float*)d_in[0];
    const float* Wq = (const float*)d_in[1];
    const float* bq = (const float*)d_in[2];
    const float* Wk = (const float*)d_in[3];
    const float* bk = (const float*)d_in[4];
    const float* Wv = (const float*)d_in[5];
    const float* bv = (const float*)d_in[6];
    const float* Wo = (const float*)d_in[7];
    const float* bo = (const float*)d_in[8];
    float* out = (float*)d_out;

    char* ws = (char*)d_ws;
    unsigned short* Xb = (unsigned short*)ws;      ws += (size_t)MTOT * KDIM * 2;
    unsigned short* Wqkvt = (unsigned short*)ws;   ws += (size_t)NQKV * KDIM * 2;
    unsigned short* Wot = (unsigned short*)ws;     ws += (size_t)EMB * KDIM * 2;
    float* biasq = (float*)ws;                     ws += (size_t)NQKV * 4;
    unsigned short* QKV = (unsigned short*)ws;     ws += (size_t)MTOT * NQKV * 2;
    unsigned short* Vt = (unsigned short*)ws;      ws += (size_t)2 * NKVH * HD * S_LEN * 2;
    unsigned short* AO = (unsigned short*)ws;      ws += (size_t)MTOT * EMB * 2;

    transpose_all<<<dim3(113, 32), 256, 0, stream>>>(Wq, Wk, Wv, Wo, bq, bk, bv, datas,
                                                     Wqkvt, Wot, biasq, Xb);

    gemm_bt<true><<<dim3(NQKV / 128, MTOT / 128), 256, 0, stream>>>(Xb, Wqkvt, biasq, QKV, NQKV);
    transpose_v<<<dim3(S_LEN / 64, NKVH, 2), 256, 0, stream>>>(QKV, Vt);
    attn<<<dim3(S_LEN / 256, NH, 2), 512, 0, stream>>>(QKV, Vt, AO);
    gemm_bt<false><<<dim3(EMB / 128, MTOT / 128), 256, 0, stream>>>(AO, Wot, bo, out, EMB);
}

// Round 22
// 211.354 us; speedup vs baseline: 1.0627x; 1.0008x over previous
//
#include <hip/hip_runtime.h>
#include <hip/hip_bf16.h>
#include <stdint.h>

// GQA prefill, all GEMM-shaped work on bf16 MFMA (16x16x32), fp32 accum.
// B=2 S=2048 E=2048 H=32 KVH=8 D=64 G=4.
// R22: exact revert to R20 (211.5 µs proven). R21 was the THIRD failure
//      (~2e-2 signature) of the "two body instances per barrier" family
//      (R13/R14/R21) — family closed; mechanism not understood, no 4th try.

#define S_LEN 2048
#define EMB   2048
#define NH    32
#define NKVH  8
#define HD    64
#define MTOT  4096            // B*S
#define NQKV  3072            // E + 2*KVH*D
#define KDIM  2048
#define QSCALE 0.18033688011112042f   // 0.125 * log2(e)

typedef __attribute__((ext_vector_type(8))) short short8;
typedef __attribute__((ext_vector_type(4))) float f32x4;
typedef __attribute__((ext_vector_type(4))) unsigned int u32x4;
typedef unsigned int u32;

__device__ __forceinline__ unsigned short f2bf(float x) {
    unsigned int u = __builtin_bit_cast(unsigned int, x);
    u = (u + 0x7FFFu + ((u >> 16) & 1u)) >> 16;   // RTN-even
    return (unsigned short)u;
}

// v_cvt_pk_bf16_f32: low16 = bf16(a), high16 = bf16(b)
__device__ __forceinline__ u32 cvtpk_bf16(float a, float b) {
    u32 r;
    asm("v_cvt_pk_bf16_f32 %0, %1, %2" : "=v"(r) : "v"(a), "v"(b));
    return r;
}

// raw v_exp_f32 (2^x); args bounded (|x| < ~40) so no OCML wrapper needed
__device__ __forceinline__ float exp2_raw(float x) {
#if __has_builtin(__builtin_amdgcn_exp2f)
    return __builtin_amdgcn_exp2f(x);
#else
    float r;
    asm("v_exp_f32 %0, %1" : "=v"(r) : "v"(x));
    return r;
#endif
}

__device__ __forceinline__ float rcp_raw(float x) {
#if __has_builtin(__builtin_amdgcn_rcpf)
    return __builtin_amdgcn_rcpf(x);
#else
    float r;
    asm("v_rcp_f32 %0, %1" : "=v"(r) : "v"(x));
    return r;
#endif
}

#define GLOAD(src, dst)                                                                   \
    __builtin_amdgcn_global_load_lds((const __attribute__((address_space(1))) void*)(src),\
                                     (__attribute__((address_space(3))) void*)(dst), 16, 0, 0)

// --------- fused preprocessing: X cvt + all 4 weight transposes + bias concat ---------
// blockIdx.x: [0,32) Wq | [32,40) Wk | [40,48) Wv | [48,80) Wo | 80 = bias |
//             [81,113) = X fp32->bf16 (chunk id (x-81)*32 + y, 2048 float4 each).
__global__ void transpose_all(const float* __restrict__ Wq, const float* __restrict__ Wk,
                              const float* __restrict__ Wv, const float* __restrict__ Wo,
                              const float* __restrict__ bq, const float* __restrict__ bk,
                              const float* __restrict__ bv, const float* __restrict__ X,
                              unsigned short* __restrict__ Wqkvt, unsigned short* __restrict__ Wot,
                              float* __restrict__ biasq, unsigned short* __restrict__ Xb) {
    const int x = blockIdx.x;
    if (x >= 81) {
        const int chunk = (x - 81) * 32 + blockIdx.y;     // 0..1023
        const int base = chunk * 2048;                    // float4 units
        #pragma unroll
        for (int j = 0; j < 8; j++) {
            int i = base + j * 256 + threadIdx.x;
            float4 v = ((const float4*)X)[i];
            ushort4 r;
            r.x = f2bf(v.x); r.y = f2bf(v.y); r.z = f2bf(v.z); r.w = f2bf(v.w);
            ((ushort4*)Xb)[i] = r;
        }
        return;
    }
    if (x == 80) {
        if (blockIdx.y == 0)
            for (int i = threadIdx.x; i < NQKV; i += 256) {
                if (i < EMB) biasq[i] = bq[i] * QSCALE;
                else if (i < EMB + 512) biasq[i] = bk[i - EMB];
                else biasq[i] = bv[i - EMB - 512];
            }
        return;
    }
    const float* src; unsigned short* dst; int N, rowOfs, nt; float scale;
    if (x < 32)      { src = Wq; dst = Wqkvt; N = 2048; rowOfs = 0;    nt = x;      scale = QSCALE; }
    else if (x < 40) { src = Wk; dst = Wqkvt; N = 512;  rowOfs = 2048; nt = x - 32; scale = 1.0f; }
    else if (x < 48) { src = Wv; dst = Wqkvt; N = 512;  rowOfs = 2560; nt = x - 40; scale = 1.0f; }
    else             { src = Wo; dst = Wot;   N = 2048; rowOfs = 0;    nt = x - 48; scale = 1.0f; }

    __shared__ float t[64][65];
    int n0 = nt * 64, k0 = blockIdx.y * 64;
    int c = threadIdx.x & 63, r0 = threadIdx.x >> 6;
    #pragma unroll
    for (int r = r0; r < 64; r += 4) t[r][c] = src[(size_t)(k0 + r) * N + n0 + c];
    __syncthreads();
    #pragma unroll
    for (int r = r0; r < 64; r += 4)
        dst[(size_t)(rowOfs + n0 + r) * KDIM + k0 + c] = f2bf(t[c][r] * scale);
}

// --------- transpose V slice of QKV -> Vt[b][kvh][d][s] (bf16) ---------
__global__ void transpose_v(const unsigned short* __restrict__ qkv, unsigned short* __restrict__ vt) {
    __shared__ unsigned short t[64][72];
    int s0 = blockIdx.x * 64; int kvh = blockIdx.y; int b = blockIdx.z;
    int c = threadIdx.x & 63, r0 = threadIdx.x >> 6;
    #pragma unroll
    for (int r = r0; r < 64; r += 4)
        t[r][c] = qkv[(size_t)(b * S_LEN + s0 + r) * NQKV + (EMB + NKVH * HD) + kvh * HD + c];
    __syncthreads();
    #pragma unroll
    for (int r = r0; r < 64; r += 4)
        vt[(size_t)((b * NKVH + kvh) * HD + r) * S_LEN + s0 + c] = t[c][r];
}

// --------- bf16 GEMM: A[M][2048] * Bt[N][2048]^T + bias -> C[M][N] ---------
// 128x128 tile, BK=64 (2 barriers per 64-K), XOR-swizzled LDS: row r (128B)
// holds 8 16B slots; slot s stores source col16 (s ^ (r&7)).
// XCD-aware block swizzle (grid %8==0). R17-proven.
template <bool OUT_BF16>
__global__ __launch_bounds__(256) void gemm_bt(const unsigned short* __restrict__ A,
                                               const unsigned short* __restrict__ Bt,
                                               const float* __restrict__ bias,
                                               void* __restrict__ Cout, int N) {
    __shared__ __align__(16) unsigned short As[128 * 64];
    __shared__ __align__(16) unsigned short Bs[128 * 64];
    const int t = threadIdx.x;
    const int lane = t & 63;
    const int l15 = lane & 15, hi = lane >> 4;
    const int xsw = l15 & 7;
    const int w = t >> 6;
    const int wm = (w >> 1) * 64, wn = (w & 1) * 64;

    const unsigned nbx = gridDim.x;
    const unsigned flat = blockIdx.y * nbx + blockIdx.x;
    const unsigned cpx = (nbx * gridDim.y) >> 3;           // nwg/8; nwg%8==0
    const unsigned swz = (flat & 7u) * cpx + (flat >> 3);  // XCD-contiguous tiles
    const int m0 = (int)(swz / nbx) * 128, n0 = (int)(swz % nbx) * 128;

    const int srow = t >> 3;                     // 0..31 (chunk adds c*32)
    const int scol = ((t & 7) ^ (srow & 7)) * 8; // pre-swizzled source col (elems)
    const unsigned short* ag[4];
    const unsigned short* bg[4];
    #pragma unroll
    for (int c = 0; c < 4; c++) {
        ag[c] = A  + (size_t)(m0 + c * 32 + srow) * KDIM + scol;
        bg[c] = Bt + (size_t)(n0 + c * 32 + srow) * KDIM + scol;
    }

    f32x4 acc[4][4] = {};

    for (int k0 = 0; k0 < KDIM; k0 += 64) {
        #pragma unroll
        for (int c = 0; c < 4; c++) {
            GLOAD(ag[c] + k0, As + c * 2048 + t * 8);
            GLOAD(bg[c] + k0, Bs + c * 2048 + t * 8);
        }
        __syncthreads();
        #pragma unroll
        for (int ks = 0; ks < 2; ks++) {
            short8 af[4], bf[4];
            #pragma unroll
            for (int m = 0; m < 4; m++)
                af[m] = *(const short8*)(As + (wm + m * 16 + l15) * 64 + (((ks * 4 + hi) ^ xsw) * 8));
            #pragma unroll
            for (int n = 0; n < 4; n++)
                bf[n] = *(const short8*)(Bs + (wn + n * 16 + l15) * 64 + (((ks * 4 + hi) ^ xsw) * 8));
            __builtin_amdgcn_s_setprio(1);
            #pragma unroll
            for (int m = 0; m < 4; m++)
                #pragma unroll
                for (int n = 0; n < 4; n++)
                    acc[m][n] = __builtin_amdgcn_mfma_f32_16x16x32_bf16(af[m], bf[n], acc[m][n], 0, 0, 0);
            __builtin_amdgcn_s_setprio(0);
        }
        __syncthreads();
    }

    #pragma unroll
    for (int m = 0; m < 4; m++) {
        int row = m0 + wm + m * 16 + hi * 4;
        #pragma unroll
        for (int n = 0; n < 4; n++) {
            int col = n0 + wn + n * 16 + l15;
            float bb = bias[col];
            #pragma unroll
            for (int i = 0; i < 4; i++) {
                float v = acc[m][n][i] + bb;
                if (OUT_BF16) ((unsigned short*)Cout)[(size_t)(row + i) * N + col] = f2bf(v);
                else          ((float*)Cout)[(size_t)(row + i) * N + col] = v;
            }
        }
    }
}

// --------- flash attention: 8 waves x 32 q-rows, shared K/V dbuf, no-max softmax ---------
// R12-proven ROLLED loop (runtime buffer index) — one body per barrier (R13/R14/R21).
__global__ __launch_bounds__(512, 4) void attn(const unsigned short* __restrict__ qkv,
                                               const unsigned short* __restrict__ vt,
                                               unsigned short* __restrict__ out) {
    constexpr int NT = S_LEN / 64;
    const int qt = blockIdx.x, h = blockIdx.y, b = blockIdx.z;
    const int kvh = h >> 2;
    const int t = threadIdx.x, lane = t & 63, w = t >> 6;
    const int l15 = lane & 15, hi = lane >> 4;
    const int xsw = l15 & 7;

    __shared__ __align__(16) unsigned short Ks[2][64 * 64];
    __shared__ __align__(16) unsigned short Vs[2][64 * 64];

    // shfl source lanes for the P repack (R3-proven)
    const int grpA = ((hi & 1) << 1) | (hi >> 1);
    const int laneA = l15 + grpA * 16;
    const int laneB = laneA ^ 16;
    const bool top = hi >= 2;

    // bf16 ones fragment for the column-sum MFMA; persistent zero C
    u32x4 onesw;
    onesw[0] = 0x3F803F80u; onesw[1] = 0x3F803F80u; onesw[2] = 0x3F803F80u; onesw[3] = 0x3F803F80u;
    const short8 ones = __builtin_bit_cast(short8, onesw);
    const f32x4 fzero = {};

    const int qrow0 = b * S_LEN + qt * 256 + w * 32;
    short8 qf[2][2];  // [nt][ks]
    #pragma unroll
    for (int nt = 0; nt < 2; nt++)
        #pragma unroll
        for (int ks = 0; ks < 2; ks++)
            qf[nt][ks] = *(const short8*)(qkv + (size_t)(qrow0 + nt * 16 + l15) * NQKV + h * HD + ks * 32 + hi * 8);

    f32x4 o[4][2] = {};              // [dt][nt]
    f32x4 osum[2] = {};              // column sums of P

    const unsigned short* kbase = qkv + (size_t)b * S_LEN * NQKV + EMB + kvh * HD;
    const unsigned short* vbase = vt + (size_t)(b * NKVH + kvh) * HD * S_LEN;

    // staging source pointers (source pre-swizzled so linear LDS dest + XOR read works)
    const int sr = t >> 3;                       // dest row (0..63)
    const int sc16 = ((t & 7) ^ (sr & 7)) * 8;   // pre-swizzled source col (shorts)
    const unsigned short* kg0 = kbase + (size_t)sr * NQKV + sc16;
    const unsigned short* vg0 = vbase + (size_t)sr * S_LEN + sc16;

#define STAGE(buf, kv0)                                               \
    do {                                                              \
        GLOAD(kg0 + (size_t)(kv0) * NQKV, &Ks[buf][t * 8]);           \
        GLOAD(vg0 + (kv0),                &Vs[buf][t * 8]);           \
    } while (0)

    STAGE(0, 0);
    __syncthreads();

    for (int tt = 0; tt < NT; tt++) {
        const int cur = tt & 1;
        if (tt + 1 < NT) STAGE(cur ^ 1, (tt + 1) * 64);

        const unsigned short* Kc = Ks[cur];
        const unsigned short* Vc = Vs[cur];

        // ---- S^T = K Q^T (log2 units); ks=0 uses zero C (no per-tile re-init) ----
        f32x4 sc[4][2];              // [mt(k)][nt(q)]
        {
            short8 kf[4];
            #pragma unroll
            for (int mt = 0; mt < 4; mt++)
                kf[mt] = *(const short8*)(Kc + (mt * 16 + l15) * 64 + ((hi ^ xsw) * 8));
            __builtin_amdgcn_s_setprio(1);
            #pragma unroll
            for (int mt = 0; mt < 4; mt++)
                #pragma unroll
                for (int nt = 0; nt < 2; nt++)
                    sc[mt][nt] = __builtin_amdgcn_mfma_f32_16x16x32_bf16(kf[mt], qf[nt][0], fzero, 0, 0, 0);
            __builtin_amdgcn_s_setprio(0);
        }
        {
            short8 kf[4];
            #pragma unroll
            for (int mt = 0; mt < 4; mt++)
                kf[mt] = *(const short8*)(Kc + (mt * 16 + l15) * 64 + (((4 + hi) ^ xsw) * 8));
            __builtin_amdgcn_s_setprio(1);
            #pragma unroll
            for (int mt = 0; mt < 4; mt++)
                #pragma unroll
                for (int nt = 0; nt < 2; nt++)
                    sc[mt][nt] = __builtin_amdgcn_mfma_f32_16x16x32_bf16(kf[mt], qf[nt][1], sc[mt][nt], 0, 0, 0);
            __builtin_amdgcn_s_setprio(0);
        }

        // ---- P = exp2(S) elementwise (raw v_exp_f32); pack to bf16 ----
        u32 w0[4][2], w1[4][2];      // packed bf16 P pairs [mt][nt]
        #pragma unroll
        for (int nt = 0; nt < 2; nt++)
            #pragma unroll
            for (int mt = 0; mt < 4; mt++) {
                #pragma unroll
                for (int i = 0; i < 4; i++)
                    sc[mt][nt][i] = exp2_raw(sc[mt][nt][i]);
                w0[mt][nt] = cvtpk_bf16(sc[mt][nt][0], sc[mt][nt][1]);
                w1[mt][nt] = cvtpk_bf16(sc[mt][nt][2], sc[mt][nt][3]);
            }

        // ---- in-register P repack (shfl) + O += V^T P, sum += 1^T P ----
        #pragma unroll
        for (int ks = 0; ks < 2; ks++) {
            short8 vf[4];
            #pragma unroll
            for (int dt = 0; dt < 4; dt++)
                vf[dt] = *(const short8*)(Vc + (dt * 16 + l15) * 64 + (((ks * 4 + hi) ^ xsw) * 8));
            #pragma unroll
            for (int nt = 0; nt < 2; nt++) {
                u32 a0 = (hi & 1) ? w0[2 * ks + 1][nt] : w0[2 * ks][nt];
                u32 a1 = (hi & 1) ? w1[2 * ks + 1][nt] : w1[2 * ks][nt];
                u32 b0 = (hi & 1) ? w0[2 * ks][nt] : w0[2 * ks + 1][nt];
                u32 b1 = (hi & 1) ? w1[2 * ks][nt] : w1[2 * ks + 1][nt];
                u32 r0 = (u32)__shfl((int)a0, laneA);
                u32 r1 = (u32)__shfl((int)a1, laneA);
                u32 r2 = (u32)__shfl((int)b0, laneB);
                u32 r3 = (u32)__shfl((int)b1, laneB);
                u32x4 pw;
                pw[0] = top ? r2 : r0;
                pw[1] = top ? r3 : r1;
                pw[2] = top ? r0 : r2;
                pw[3] = top ? r1 : r3;
                short8 pa = __builtin_bit_cast(short8, pw);
                __builtin_amdgcn_s_setprio(1);
                osum[nt] = __builtin_amdgcn_mfma_f32_16x16x32_bf16(ones, pa, osum[nt], 0, 0, 0);
                #pragma unroll
                for (int dt = 0; dt < 4; dt++)
                    o[dt][nt] = __builtin_amdgcn_mfma_f32_16x16x32_bf16(vf[dt], pa, o[dt][nt], 0, 0, 0);
                __builtin_amdgcn_s_setprio(0);
            }
        }
        __syncthreads();   // drains stage(tt+1) vmem; protects buffer reuse
    }
#undef STAGE

    // ---- normalize + write (O^T layout: row=d, col=q); packed stores ----
    #pragma unroll
    for (int nt = 0; nt < 2; nt++) {
        float inv = rcp_raw(osum[nt][0]);
        size_t rbase = (size_t)(qrow0 + nt * 16 + l15) * EMB + h * HD;
        #pragma unroll
        for (int dt = 0; dt < 4; dt++) {
            uint2 pk;
            pk.x = cvtpk_bf16(o[dt][nt][0] * inv, o[dt][nt][1] * inv);
            pk.y = cvtpk_bf16(o[dt][nt][2] * inv, o[dt][nt][3] * inv);
            *(uint2*)(out + rbase + dt * 16 + hi * 4) = pk;
        }
    }
}

extern "C" void kernel_launch(void* const* d_in, const int* in_sizes, int n_in,
                              void* d_out, int out_size, void* d_ws, size_t ws_size,
                              hipStream_t stream) {
    const float* datas = (const float*)d_in[0];
    const float* Wq = (const float*)d_in[1];
    const float* bq = (const float*)d_in[2];
    const float* Wk = (const float*)d_in[3];
    const float* bk = (const float*)d_in[4];
    const float* Wv = (const float*)d_in[5];
    const float* bv = (const float*)d_in[6];
    const float* Wo = (const float*)d_in[7];
    const float* bo = (const float*)d_in[8];
    float* out = (float*)d_out;

    char* ws = (char*)d_ws;
    unsigned short* Xb = (unsigned short*)ws;      ws += (size_t)MTOT * KDIM * 2;
    unsigned short* Wqkvt = (unsigned short*)ws;   ws += (size_t)NQKV * KDIM * 2;
    unsigned short* Wot = (unsigned short*)ws;     ws += (size_t)EMB * KDIM * 2;
    float* biasq = (float*)ws;                     ws += (size_t)NQKV * 4;
    unsigned short* QKV = (unsigned short*)ws;     ws += (size_t)MTOT * NQKV * 2;
    unsigned short* Vt = (unsigned short*)ws;      ws += (size_t)2 * NKVH * HD * S_LEN * 2;
    unsigned short* AO = (unsigned short*)ws;      ws += (size_t)MTOT * EMB * 2;

    transpose_all<<<dim3(113, 32), 256, 0, stream>>>(Wq, Wk, Wv, Wo, bq, bk, bv, datas,
                                                     Wqkvt, Wot, biasq, Xb);

    gemm_bt<true><<<dim3(NQKV / 128, MTOT / 128), 256, 0, stream>>>(Xb, Wqkvt, biasq, QKV, NQKV);
    transpose_v<<<dim3(S_LEN / 64, NKVH, 2), 256, 0, stream>>>(QKV, Vt);
    attn<<<dim3(S_LEN / 256, NH, 2), 512, 0, stream>>>(QKV, Vt, AO);
    gemm_bt<false><<<dim3(EMB / 128, MTOT / 128), 256, 0, stream>>>(AO, Wot, bo, out, EMB);
}